// Round 6
// baseline (203.256 us; speedup 1.0000x reference)
//
#include <hip/hip_runtime.h>
#include <hip/hip_bf16.h>

typedef unsigned short u16;
typedef u16 us4 __attribute__((ext_vector_type(4)));
typedef u16 us8 __attribute__((ext_vector_type(8)));
typedef __bf16 bf16x8 __attribute__((ext_vector_type(8)));
typedef float f32x4 __attribute__((ext_vector_type(4)));

#define NDIM 4096
#define HDIM 2048

__device__ __forceinline__ u16 bfbits(float f) {
    __hip_bfloat16 h = __float2bfloat16(f);
    return __builtin_bit_cast(u16, h);
}
__device__ __forceinline__ float bf2f(u16 b) {
    return __builtin_bit_cast(float, ((unsigned)b) << 16);
}

__device__ __forceinline__ void gload_lds16(const u16* g, u16* l) {
    __builtin_amdgcn_global_load_lds((__attribute__((address_space(1))) void*)g,
                                     (__attribute__((address_space(3))) void*)l,
                                     16, 0, 0);
}

// ---------------------------------------------------------------------------
// Ce[u][k'] = cos(pi*k'*(u+0.5)/2048), Co[u][k'] = cos(pi*(2k'+1)*(u+0.5)/4096)
__global__ __launch_bounds__(256) void k_gencos2(u16* __restrict__ Ce, u16* __restrict__ Co) {
    int idx = blockIdx.x * 256 + threadIdx.x;
    int u = idx >> 8;
    int k0 = (idx & 255) * 8;
    unsigned step = (unsigned)(2 * u + 1);
    us8 e, o;
#pragma unroll
    for (int i = 0; i < 8; ++i) {
        unsigned kk = (unsigned)(k0 + i);
        unsigned te = (2u * kk * step) & 16383u;
        unsigned to = ((2u * kk + 1u) * step) & 16383u;
        e[i] = bfbits(cosf((float)te * 3.8349519697141029e-4f)); // 2pi/16384
        o[i] = bfbits(cosf((float)to * 3.8349519697141029e-4f));
    }
    *(us8*)&Ce[(size_t)idx * 8] = e;
    *(us8*)&Co[(size_t)idx * 8] = o;
}

// ---------------------------------------------------------------------------
// Xe[j][k'] = bf16(X[2k'][j]), Xo[j][k'] = bf16(X[2k'+1][j])
__global__ __launch_bounds__(256) void k_transpose_split(const float* __restrict__ X,
                                                         u16* __restrict__ Xe,
                                                         u16* __restrict__ Xo) {
    __shared__ float tile[64][65];
    int b  = blockIdx.x;
    int bx = (b & 63) * 64;
    int by = (b >> 6) * 64;
    int t  = threadIdx.x;
    int lr = t >> 4, lc = (t & 15) * 4;
#pragma unroll
    for (int r = 0; r < 64; r += 16) {
        float4 v = *(const float4*)&X[(size_t)(by + lr + r) * NDIM + bx + lc];
        tile[lr + r][lc + 0] = v.x;
        tile[lr + r][lc + 1] = v.y;
        tile[lr + r][lc + 2] = v.z;
        tile[lr + r][lc + 3] = v.w;
    }
    __syncthreads();
    int jl = t >> 2;
    int s8 = (t & 3) * 8;
    us8 e, o;
#pragma unroll
    for (int i = 0; i < 8; ++i) {
        e[i] = bfbits(tile[2 * (s8 + i)][jl]);
        o[i] = bfbits(tile[2 * (s8 + i) + 1][jl]);
    }
    size_t base = (size_t)(bx + jl) * HDIM + (by >> 1) + s8;
    *(us8*)&Xe[base] = e;
    *(us8*)&Xo[base] = o;
}

// ---------------------------------------------------------------------------
// Butterfly 1: W[u] = S[u]+D[u], W[4095-u] = S[u]-D[u], column-deinterleaved.
__global__ __launch_bounds__(256) void k_bfly1(const u16* __restrict__ S,
                                               const u16* __restrict__ D,
                                               u16* __restrict__ We,
                                               u16* __restrict__ Wo) {
    int idx = blockIdx.x * 256 + threadIdx.x;
    int u  = idx >> 9;
    int j0 = (idx & 511) * 8;
    us8 s8 = *(const us8*)&S[(size_t)u * NDIM + j0];
    us8 d8 = *(const us8*)&D[(size_t)u * NDIM + j0];
    us4 et, ot, eb, ob;
#pragma unroll
    for (int i = 0; i < 4; ++i) {
        float se = bf2f(s8[2 * i]),     de = bf2f(d8[2 * i]);
        float so = bf2f(s8[2 * i + 1]), dd = bf2f(d8[2 * i + 1]);
        et[i] = bfbits(se + de);  eb[i] = bfbits(se - de);
        ot[i] = bfbits(so + dd);  ob[i] = bfbits(so - dd);
    }
    size_t ct = (size_t)u * HDIM + (j0 >> 1);
    size_t cb = (size_t)(NDIM - 1 - u) * HDIM + (j0 >> 1);
    *(us4*)&We[ct] = et;  *(us4*)&Wo[ct] = ot;
    *(us4*)&We[cb] = eb;  *(us4*)&Wo[cb] = ob;
}

// ---------------------------------------------------------------------------
// Butterfly 2: Y[i][v'] = S2+D2, Y[i][4095-v'] = S2-D2, f32 out.
__global__ __launch_bounds__(256) void k_bfly2(const u16* __restrict__ S2,
                                               const u16* __restrict__ D2,
                                               float* __restrict__ Y) {
    int idx = blockIdx.x * 256 + threadIdx.x;
    int i  = idx >> 8;
    int v0 = (idx & 255) * 8;
    us8 s8 = *(const us8*)&S2[(size_t)i * HDIM + v0];
    us8 d8 = *(const us8*)&D2[(size_t)i * HDIM + v0];
    float sum[8], dif[8];
#pragma unroll
    for (int t = 0; t < 8; ++t) {
        float s = bf2f(s8[t]), d = bf2f(d8[t]);
        sum[t] = s + d;  dif[t] = s - d;
    }
    f32x4 a0, a1, r0, r1;
#pragma unroll
    for (int w = 0; w < 4; ++w) {
        a0[w] = sum[w];  a1[w] = sum[w + 4];
        r0[w] = dif[7 - w];  r1[w] = dif[3 - w];
    }
    float* row = Y + (size_t)i * NDIM;
    *(f32x4*)&row[v0]        = a0;
    *(f32x4*)&row[v0 + 4]    = a1;
    *(f32x4*)&row[4088 - v0] = r0;
    *(f32x4*)&row[4092 - v0] = r1;
}

// ---------------------------------------------------------------------------
// D = A @ B^T, 256x256 tile, BK=64, 8 waves, 8-phase schedule.
// r6: one-phase-ahead ds_read prefetch ISSUED AT PHASE TOP (prio-0 region,
// pre-barrier) so the LDS drain of phase P+1's operands overlaps phase P's
// MFMA window. vmcnt(4) certification at ph4/ph8 TOP (FIFO ledger verified).
// Stage schedule identical to proven r4 ledger. Phase MFMA quadrants:
// (m-half, k-half) -> per-acc K order unchanged (bitwise-same out, canary 64).
#define BAR() do { asm volatile("" ::: "memory"); __builtin_amdgcn_s_barrier(); \
                   asm volatile("" ::: "memory"); } while (0)
#define BARS() do { BAR(); __builtin_amdgcn_sched_barrier(0); } while (0)
#define WAITV(N) asm volatile("s_waitcnt vmcnt(" #N ")" ::: "memory")

template <int NTK, int LOG_NTN>
__global__ __launch_bounds__(512, 2) void gemm256h(const u16* __restrict__ A0,
                                                   const u16* __restrict__ A1,
                                                   const u16* __restrict__ B0,
                                                   const u16* __restrict__ B1,
                                                   u16* __restrict__ out) {
    constexpr int KD  = NTK * 64;
    constexpr int NTN = 1 << LOG_NTN;
    constexpr int LDC = NTN * 256;
    constexpr int MTILES = 128 >> LOG_NTN;

    __shared__ u16 As[2 * 256 * 64];
    __shared__ u16 Bs[2 * 256 * 64];

    const int tid  = threadIdx.x;
    const int wave = tid >> 6;
    const int lane = tid & 63;

    const int bid = blockIdx.x;
    const int swz = (bid & 7) * 32 + (bid >> 3);   // grid 256, bijective
    const int half = swz >> 7;
    const int r    = swz & 127;
    const int bm   = (r >> LOG_NTN) * 256;
    const int bn   = (r & (NTN - 1)) * 256;

    const u16* A = half ? A1 : A0;
    const u16* B = half ? B1 : B0;
    u16* Cp = out + (size_t)half * MTILES * 256 * LDC;

    const int wr = wave >> 2;
    const int wc = wave & 3;

    const int srow = lane >> 3;
    const int scol = ((lane & 7) ^ srow) << 3;     // pre-swizzled global col offset

    const int fr   = lane & 15;
    const int hi   = lane >> 4;
    const int slot0 = ((hi)     ^ (lane & 7)) << 3;   // k-half 0
    const int slot1 = ((hi + 4) ^ (lane & 7)) << 3;   // k-half 1
    const int aRow = (wr * 128 + fr) * 64;
    const int bRow = (wc * 64 + fr) * 64;

    f32x4 acc[8][4] = {};
    bf16x8 aX[4], aY[4], bb0[4], bb1[4];   // ping-pong A sets; k0/k1 B sets

#define STAGE_A(TK, H, BOFF)                                                     \
    do {                                                                         \
        const int _tk = (TK) & (NTK - 1);                                        \
        _Pragma("unroll")                                                        \
        for (int q = 0; q < 2; ++q) {                                            \
            const int seg  = wave * 2 + q;                                       \
            const int row0 = (H) * 64 + (seg & 7) * 8 + (seg >> 3) * 128;        \
            const u16* _g = A + (size_t)(bm + row0 + srow) * KD + _tk * 64 + scol; \
            gload_lds16(_g, As + (BOFF) + row0 * 64 + lane * 8);                 \
        }                                                                        \
    } while (0)

#define STAGE_B(TK, H, BOFF)                                                     \
    do {                                                                         \
        const int _tk = (TK) & (NTK - 1);                                        \
        _Pragma("unroll")                                                        \
        for (int q = 0; q < 2; ++q) {                                            \
            const int seg  = wave * 2 + q;                                       \
            const int row0 = (H) * 32 + (seg & 3) * 8 + (seg >> 2) * 64;         \
            const u16* _g = B + (size_t)(bn + row0 + srow) * KD + _tk * 64 + scol; \
            gload_lds16(_g, Bs + (BOFF) + row0 * 64 + lane * 8);                 \
        }                                                                        \
    } while (0)

#define RD_A(DST, MB, SL, BOFF)                                                 \
    _Pragma("unroll")                                                           \
    for (int mm = 0; mm < 4; ++mm)                                              \
        DST[mm] = __builtin_bit_cast(bf16x8, *(const us8*)(As + (BOFF) + aRow + ((MB) + mm) * 1024 + (SL)));

#define RD_B(DST, SL, BOFF)                                                     \
    _Pragma("unroll")                                                           \
    for (int nn = 0; nn < 4; ++nn)                                              \
        DST[nn] = __builtin_bit_cast(bf16x8, *(const us8*)(Bs + (BOFF) + bRow + nn * 1024 + (SL)));

#define MFMA16(MB, AREG, BREG)                                                  \
    do {                                                                        \
        __builtin_amdgcn_s_setprio(1);                                          \
        _Pragma("unroll")                                                       \
        for (int mm = 0; mm < 4; ++mm)                                          \
            _Pragma("unroll")                                                   \
            for (int nn = 0; nn < 4; ++nn)                                      \
                acc[(MB)+mm][nn] = __builtin_amdgcn_mfma_f32_16x16x32_bf16(AREG[mm], BREG[nn], acc[(MB)+mm][nn], 0, 0, 0); \
        __builtin_amdgcn_s_setprio(0);                                          \
    } while (0)

    // ---- prologue: 7 halves (r4 ledger); vmcnt(6) completes tile 0
    STAGE_B(0, 0, 0);
    STAGE_A(0, 0, 0);
    STAGE_B(0, 1, 0);
    STAGE_A(0, 1, 0);
    STAGE_B(1, 0, 16384);
    STAGE_A(1, 0, 16384);
    STAGE_B(1, 1, 16384);
    WAITV(6);
    BAR();
    RD_A(aX, 0, slot0, 0);     // ph1 operands: m0-3, k0, buf0
    RD_B(bb0, slot0, 0);       // n0-3, k0, buf0

    for (int t = 0; t < NTK; t += 2) {
        // ph1: rd aY(m4-7,k0,b0); stage A(t+1)h1->b1; MFMA(acc0-3, aX, bb0)
        RD_A(aY, 4, slot0, 0);
        STAGE_A(t + 1, 1, 16384);
        BARS();
        MFMA16(0, aX, bb0);
        BAR();
        // ph2: rd aX(m0-3,k1,b0)+bb1(k1,b0); stage B(t+2)h0->b0; MFMA(acc4-7, aY, bb0)
        RD_A(aX, 0, slot1, 0);
        RD_B(bb1, slot1, 0);
        STAGE_B(t + 2, 0, 0);
        BARS();
        MFMA16(4, aY, bb0);
        BAR();
        // ph3: rd aY(m4-7,k1,b0); stage A(t+2)h0->b0; MFMA(acc0-3, aX, bb1)
        RD_A(aY, 4, slot1, 0);
        STAGE_A(t + 2, 0, 0);
        BARS();
        MFMA16(0, aX, bb1);
        BAR();
        // ph4: WAITV(4) certifies tile t+1 (buf1); rd aX(m0-3,k0,b1)+bb0(k0,b1);
        //      stage B(t+2)h1->b0; MFMA(acc4-7, aY, bb1)
        WAITV(4);
        RD_A(aX, 0, slot0, 16384);
        RD_B(bb0, slot0, 16384);
        STAGE_B(t + 2, 1, 0);
        BARS();
        MFMA16(4, aY, bb1);
        BAR();
        // ph5: rd aY(m4-7,k0,b1); stage A(t+2)h1->b0; MFMA(acc0-3, aX, bb0)
        RD_A(aY, 4, slot0, 16384);
        STAGE_A(t + 2, 1, 0);
        BARS();
        MFMA16(0, aX, bb0);
        BAR();
        // ph6: rd aX(m0-3,k1,b1)+bb1(k1,b1); stage B(t+3)h0->b1; MFMA(acc4-7, aY, bb0)
        RD_A(aX, 0, slot1, 16384);
        RD_B(bb1, slot1, 16384);
        STAGE_B(t + 3, 0, 16384);
        BARS();
        MFMA16(4, aY, bb0);
        BAR();
        // ph7: rd aY(m4-7,k1,b1); stage A(t+3)h0->b1; MFMA(acc0-3, aX, bb1)
        RD_A(aY, 4, slot1, 16384);
        STAGE_A(t + 3, 0, 16384);
        BARS();
        MFMA16(0, aX, bb1);
        BAR();
        // ph8: WAITV(4) certifies tile t+2 (buf0); rd aX(m0-3,k0,b0)+bb0(k0,b0);
        //      stage B(t+3)h1->b1; MFMA(acc4-7, aY, bb1)
        WAITV(4);
        RD_A(aX, 0, slot0, 0);
        RD_B(bb0, slot0, 0);
        STAGE_B(t + 3, 1, 16384);
        BARS();
        MFMA16(4, aY, bb1);
        BAR();
    }

    asm volatile("s_waitcnt vmcnt(0)" ::: "memory");

    const int orow0 = wr * 128 + hi * 4;
    const int ocol0 = bn + wc * 64 + fr;
#pragma unroll
    for (int m = 0; m < 8; ++m)
#pragma unroll
        for (int n = 0; n < 4; ++n) {
            f32x4 v = acc[m][n];
#pragma unroll
            for (int rr = 0; rr < 4; ++rr) {
                size_t off = (size_t)(bm + orow0 + m * 16 + rr) * LDC + (ocol0 + n * 16);
                Cp[off] = bfbits(v[rr]);
            }
        }
#undef STAGE_A
#undef STAGE_B
#undef RD_A
#undef RD_B
#undef MFMA16
}

// ---------------------------------------------------------------------------
extern "C" void kernel_launch(void* const* d_in, const int* in_sizes, int n_in,
                              void* d_out, int out_size, void* d_ws, size_t ws_size,
                              hipStream_t stream) {
    const float* X = (const float*)d_in[0];
    float* Y = (float*)d_out;

    const size_t QM = (size_t)HDIM * HDIM;
    u16* Ce = (u16*)d_ws;
    u16* Co = Ce + QM;
    u16* Xe = Co + QM;
    u16* Xo = Xe + 2 * QM;
    u16* S  = Xo + 2 * QM;
    u16* D  = S + 2 * QM;
    u16* We = Xe;
    u16* Wo = Xo;
    u16* S2 = S;
    u16* D2 = D;

    k_gencos2<<<2048, 256, 0, stream>>>(Ce, Co);
    k_transpose_split<<<4096, 256, 0, stream>>>(X, Xe, Xo);
    gemm256h<32, 4><<<256, 512, 0, stream>>>(Ce, Co, Xe, Xo, S);
    k_bfly1<<<4096, 256, 0, stream>>>(S, D, We, Wo);
    gemm256h<32, 3><<<256, 512, 0, stream>>>(We, Wo, Ce, Co, S2);
    k_bfly2<<<4096, 256, 0, stream>>>(S2, D2, Y);
}

// Round 7
// 174.566 us; speedup vs baseline: 1.1644x; 1.1644x over previous
//
#include <hip/hip_runtime.h>
#include <hip/hip_bf16.h>

typedef unsigned short u16;
typedef u16 us4 __attribute__((ext_vector_type(4)));
typedef u16 us8 __attribute__((ext_vector_type(8)));
typedef __bf16 bf16x8 __attribute__((ext_vector_type(8)));
typedef float f32x4 __attribute__((ext_vector_type(4)));

#define NDIM 4096
#define HDIM 2048

__device__ __forceinline__ u16 bfbits(float f) {
    __hip_bfloat16 h = __float2bfloat16(f);
    return __builtin_bit_cast(u16, h);
}
__device__ __forceinline__ float bf2f(u16 b) {
    return __builtin_bit_cast(float, ((unsigned)b) << 16);
}

__device__ __forceinline__ void gload_lds16(const u16* g, u16* l) {
    __builtin_amdgcn_global_load_lds((__attribute__((address_space(1))) void*)g,
                                     (__attribute__((address_space(3))) void*)l,
                                     16, 0, 0);
}

// ---------------------------------------------------------------------------
// Ce[u][k'] = cos(pi*k'*(u+0.5)/2048), Co[u][k'] = cos(pi*(2k'+1)*(u+0.5)/4096)
__global__ __launch_bounds__(256) void k_gencos2(u16* __restrict__ Ce, u16* __restrict__ Co) {
    int idx = blockIdx.x * 256 + threadIdx.x;
    int u = idx >> 8;
    int k0 = (idx & 255) * 8;
    unsigned step = (unsigned)(2 * u + 1);
    us8 e, o;
#pragma unroll
    for (int i = 0; i < 8; ++i) {
        unsigned kk = (unsigned)(k0 + i);
        unsigned te = (2u * kk * step) & 16383u;
        unsigned to = ((2u * kk + 1u) * step) & 16383u;
        e[i] = bfbits(cosf((float)te * 3.8349519697141029e-4f)); // 2pi/16384
        o[i] = bfbits(cosf((float)to * 3.8349519697141029e-4f));
    }
    *(us8*)&Ce[(size_t)idx * 8] = e;
    *(us8*)&Co[(size_t)idx * 8] = o;
}

// ---------------------------------------------------------------------------
// Xe[j][k'] = bf16(X[2k'][j]), Xo[j][k'] = bf16(X[2k'+1][j])
__global__ __launch_bounds__(256) void k_transpose_split(const float* __restrict__ X,
                                                         u16* __restrict__ Xe,
                                                         u16* __restrict__ Xo) {
    __shared__ float tile[64][65];
    int b  = blockIdx.x;
    int bx = (b & 63) * 64;
    int by = (b >> 6) * 64;
    int t  = threadIdx.x;
    int lr = t >> 4, lc = (t & 15) * 4;
#pragma unroll
    for (int r = 0; r < 64; r += 16) {
        float4 v = *(const float4*)&X[(size_t)(by + lr + r) * NDIM + bx + lc];
        tile[lr + r][lc + 0] = v.x;
        tile[lr + r][lc + 1] = v.y;
        tile[lr + r][lc + 2] = v.z;
        tile[lr + r][lc + 3] = v.w;
    }
    __syncthreads();
    int jl = t >> 2;
    int s8 = (t & 3) * 8;
    us8 e, o;
#pragma unroll
    for (int i = 0; i < 8; ++i) {
        e[i] = bfbits(tile[2 * (s8 + i)][jl]);
        o[i] = bfbits(tile[2 * (s8 + i) + 1][jl]);
    }
    size_t base = (size_t)(bx + jl) * HDIM + (by >> 1) + s8;
    *(us8*)&Xe[base] = e;
    *(us8*)&Xo[base] = o;
}

// ---------------------------------------------------------------------------
// Butterfly 1: W[u] = S[u]+D[u], W[4095-u] = S[u]-D[u], column-deinterleaved.
__global__ __launch_bounds__(256) void k_bfly1(const u16* __restrict__ S,
                                               const u16* __restrict__ D,
                                               u16* __restrict__ We,
                                               u16* __restrict__ Wo) {
    int idx = blockIdx.x * 256 + threadIdx.x;
    int u  = idx >> 9;
    int j0 = (idx & 511) * 8;
    us8 s8 = *(const us8*)&S[(size_t)u * NDIM + j0];
    us8 d8 = *(const us8*)&D[(size_t)u * NDIM + j0];
    us4 et, ot, eb, ob;
#pragma unroll
    for (int i = 0; i < 4; ++i) {
        float se = bf2f(s8[2 * i]),     de = bf2f(d8[2 * i]);
        float so = bf2f(s8[2 * i + 1]), dd = bf2f(d8[2 * i + 1]);
        et[i] = bfbits(se + de);  eb[i] = bfbits(se - de);
        ot[i] = bfbits(so + dd);  ob[i] = bfbits(so - dd);
    }
    size_t ct = (size_t)u * HDIM + (j0 >> 1);
    size_t cb = (size_t)(NDIM - 1 - u) * HDIM + (j0 >> 1);
    *(us4*)&We[ct] = et;  *(us4*)&Wo[ct] = ot;
    *(us4*)&We[cb] = eb;  *(us4*)&Wo[cb] = ob;
}

// ---------------------------------------------------------------------------
// Butterfly 2: Y[i][v'] = S2+D2, Y[i][4095-v'] = S2-D2, f32 out.
__global__ __launch_bounds__(256) void k_bfly2(const u16* __restrict__ S2,
                                               const u16* __restrict__ D2,
                                               float* __restrict__ Y) {
    int idx = blockIdx.x * 256 + threadIdx.x;
    int i  = idx >> 8;
    int v0 = (idx & 255) * 8;
    us8 s8 = *(const us8*)&S2[(size_t)i * HDIM + v0];
    us8 d8 = *(const us8*)&D2[(size_t)i * HDIM + v0];
    float sum[8], dif[8];
#pragma unroll
    for (int t = 0; t < 8; ++t) {
        float s = bf2f(s8[t]), d = bf2f(d8[t]);
        sum[t] = s + d;  dif[t] = s - d;
    }
    f32x4 a0, a1, r0, r1;
#pragma unroll
    for (int w = 0; w < 4; ++w) {
        a0[w] = sum[w];  a1[w] = sum[w + 4];
        r0[w] = dif[7 - w];  r1[w] = dif[3 - w];
    }
    float* row = Y + (size_t)i * NDIM;
    *(f32x4*)&row[v0]        = a0;
    *(f32x4*)&row[v0 + 4]    = a1;
    *(f32x4*)&row[4088 - v0] = r0;
    *(f32x4*)&row[4092 - v0] = r1;
}

// ---------------------------------------------------------------------------
// D = A @ B^T, 256x256 tile, BK=64, 8 waves, 8-phase schedule, 3-half-deep
// counted-vmcnt pipeline (exact r4 structure; 66.4us known-good).
// r7 single change: MFMA_Q k-OUTER ordering -- 8 independent MFMAs between
// the two updates of any accumulator (dependent-pair stall fix). Per-acc
// K order unchanged (k0 before k1) -> bitwise-same output (canary 64).
#define BAR() do { asm volatile("" ::: "memory"); __builtin_amdgcn_s_barrier(); \
                   asm volatile("" ::: "memory"); } while (0)
#define WAITV(N) asm volatile("s_waitcnt vmcnt(" #N ")" ::: "memory")

template <int NTK, int LOG_NTN>
__global__ __launch_bounds__(512, 2) void gemm256h(const u16* __restrict__ A0,
                                                   const u16* __restrict__ A1,
                                                   const u16* __restrict__ B0,
                                                   const u16* __restrict__ B1,
                                                   u16* __restrict__ out) {
    constexpr int KD  = NTK * 64;
    constexpr int NTN = 1 << LOG_NTN;
    constexpr int LDC = NTN * 256;
    constexpr int MTILES = 128 >> LOG_NTN;

    __shared__ u16 As[2 * 256 * 64];
    __shared__ u16 Bs[2 * 256 * 64];

    const int tid  = threadIdx.x;
    const int wave = tid >> 6;
    const int lane = tid & 63;

    const int bid = blockIdx.x;
    const int swz = (bid & 7) * 32 + (bid >> 3);   // grid 256, bijective
    const int half = swz >> 7;
    const int r    = swz & 127;
    const int bm   = (r >> LOG_NTN) * 256;
    const int bn   = (r & (NTN - 1)) * 256;

    const u16* A = half ? A1 : A0;
    const u16* B = half ? B1 : B0;
    u16* Cp = out + (size_t)half * MTILES * 256 * LDC;

    const int wr = wave >> 2;
    const int wc = wave & 3;

    const int srow = lane >> 3;
    const int scol = ((lane & 7) ^ srow) << 3;     // pre-swizzled global col offset

    const int fr   = lane & 15;
    const int hi   = lane >> 4;
    const int slot0 = ((hi)     ^ (lane & 7)) << 3;
    const int slot1 = ((hi + 4) ^ (lane & 7)) << 3;
    const int aRow = (wr * 128 + fr) * 64;
    const int bRow = (wc * 64 + fr) * 64;

    f32x4 acc[8][4] = {};
    bf16x8 aR[4][2], b01[2][2], b23[2][2];

#define STAGE_A(TK, H, BOFF)                                                     \
    do {                                                                         \
        const int _tk = (TK) & (NTK - 1);                                        \
        _Pragma("unroll")                                                        \
        for (int q = 0; q < 2; ++q) {                                            \
            const int seg  = wave * 2 + q;                                       \
            const int row0 = (H) * 64 + (seg & 7) * 8 + (seg >> 3) * 128;        \
            const u16* _g = A + (size_t)(bm + row0 + srow) * KD + _tk * 64 + scol; \
            gload_lds16(_g, As + (BOFF) + row0 * 64 + lane * 8);                 \
        }                                                                        \
    } while (0)

#define STAGE_B(TK, H, BOFF)                                                     \
    do {                                                                         \
        const int _tk = (TK) & (NTK - 1);                                        \
        _Pragma("unroll")                                                        \
        for (int q = 0; q < 2; ++q) {                                            \
            const int seg  = wave * 2 + q;                                       \
            const int row0 = (H) * 32 + (seg & 3) * 8 + (seg >> 2) * 64;         \
            const u16* _g = B + (size_t)(bn + row0 + srow) * KD + _tk * 64 + scol; \
            gload_lds16(_g, Bs + (BOFF) + row0 * 64 + lane * 8);                 \
        }                                                                        \
    } while (0)

#define LOAD_A(MB, BOFF)                                                        \
    _Pragma("unroll")                                                           \
    for (int mm = 0; mm < 4; ++mm) {                                            \
        aR[mm][0] = __builtin_bit_cast(bf16x8, *(const us8*)(As + (BOFF) + aRow + ((MB) + mm) * 1024 + slot0)); \
        aR[mm][1] = __builtin_bit_cast(bf16x8, *(const us8*)(As + (BOFF) + aRow + ((MB) + mm) * 1024 + slot1)); \
    }

#define LOAD_B(DST, NB, BOFF)                                                   \
    _Pragma("unroll")                                                           \
    for (int nn = 0; nn < 2; ++nn) {                                            \
        DST[nn][0] = __builtin_bit_cast(bf16x8, *(const us8*)(Bs + (BOFF) + bRow + ((NB) + nn) * 1024 + slot0)); \
        DST[nn][1] = __builtin_bit_cast(bf16x8, *(const us8*)(Bs + (BOFF) + bRow + ((NB) + nn) * 1024 + slot1)); \
    }

// k-OUTER: 8 independent MFMAs between dependent acc updates; per-acc order
// still k0-then-k1 (bitwise identical to r4).
#define MFMA_Q(MB, NB, BREG)                                                    \
    do {                                                                        \
        __builtin_amdgcn_s_setprio(1);                                          \
        _Pragma("unroll")                                                       \
        for (int kk = 0; kk < 2; ++kk)                                          \
            _Pragma("unroll")                                                   \
            for (int mm = 0; mm < 4; ++mm)                                      \
                _Pragma("unroll")                                               \
                for (int nn = 0; nn < 2; ++nn)                                  \
                    acc[(MB)+mm][(NB)+nn] = __builtin_amdgcn_mfma_f32_16x16x32_bf16(aR[mm][kk], BREG[nn][kk], acc[(MB)+mm][(NB)+nn], 0, 0, 0); \
        __builtin_amdgcn_s_setprio(0);                                          \
    } while (0)

    // ---- prologue: 7 halves, steady-state mimic; vmcnt(6) completes tile 0
    STAGE_B(0, 0, 0);
    STAGE_A(0, 0, 0);
    STAGE_B(0, 1, 0);
    STAGE_A(0, 1, 0);
    STAGE_B(1, 0, 16384);
    STAGE_A(1, 0, 16384);
    STAGE_B(1, 1, 16384);
    WAITV(6);
    BAR();

    for (int t = 0; t < NTK; t += 2) {
        // ph1: compute t(buf0) q(m0-3,n0-1); stage A(t+1)h1' -> buf1
        LOAD_A(0, 0);
        LOAD_B(b01, 0, 0);
        STAGE_A(t + 1, 1, 16384);
        BAR();
        MFMA_Q(0, 0, b01);
        BAR();
        // ph2: q(m0-3,n2-3); stage B(t+2)h0' -> buf0
        LOAD_B(b23, 2, 0);
        STAGE_B(t + 2, 0, 0);
        BAR();
        MFMA_Q(0, 2, b23);
        BAR();
        // ph3: q(m4-7,n2-3); stage A(t+2)h0' -> buf0
        LOAD_A(4, 0);
        STAGE_A(t + 2, 0, 0);
        BAR();
        MFMA_Q(4, 2, b23);
        BAR();
        // ph4: q(m4-7,n0-1); stage B(t+2)h1' -> buf0; vmcnt(6) completes tile t+1
        STAGE_B(t + 2, 1, 0);
        BAR();
        MFMA_Q(4, 0, b01);
        WAITV(6);
        BAR();
        // ph5: compute t+1(buf1) q(m0-3,n0-1); stage A(t+2)h1' -> buf0
        LOAD_A(0, 16384);
        LOAD_B(b01, 0, 16384);
        STAGE_A(t + 2, 1, 0);
        BAR();
        MFMA_Q(0, 0, b01);
        BAR();
        // ph6: q(m0-3,n2-3); stage B(t+3)h0' -> buf1
        LOAD_B(b23, 2, 16384);
        STAGE_B(t + 3, 0, 16384);
        BAR();
        MFMA_Q(0, 2, b23);
        BAR();
        // ph7: q(m4-7,n2-3); stage A(t+3)h0' -> buf1
        LOAD_A(4, 16384);
        STAGE_A(t + 3, 0, 16384);
        BAR();
        MFMA_Q(4, 2, b23);
        BAR();
        // ph8: q(m4-7,n0-1); stage B(t+3)h1' -> buf1; vmcnt(6) completes tile t+2
        STAGE_B(t + 3, 1, 16384);
        BAR();
        MFMA_Q(4, 0, b01);
        WAITV(6);
        BAR();
    }

    asm volatile("s_waitcnt vmcnt(0)" ::: "memory");

    const int orow0 = wr * 128 + hi * 4;
    const int ocol0 = bn + wc * 64 + fr;
#pragma unroll
    for (int m = 0; m < 8; ++m)
#pragma unroll
        for (int n = 0; n < 4; ++n) {
            f32x4 v = acc[m][n];
#pragma unroll
            for (int rr = 0; rr < 4; ++rr) {
                size_t off = (size_t)(bm + orow0 + m * 16 + rr) * LDC + (ocol0 + n * 16);
                Cp[off] = bfbits(v[rr]);
            }
        }
#undef STAGE_A
#undef STAGE_B
#undef LOAD_A
#undef LOAD_B
#undef MFMA_Q
}

// ---------------------------------------------------------------------------
extern "C" void kernel_launch(void* const* d_in, const int* in_sizes, int n_in,
                              void* d_out, int out_size, void* d_ws, size_t ws_size,
                              hipStream_t stream) {
    const float* X = (const float*)d_in[0];
    float* Y = (float*)d_out;

    const size_t QM = (size_t)HDIM * HDIM;
    u16* Ce = (u16*)d_ws;
    u16* Co = Ce + QM;
    u16* Xe = Co + QM;
    u16* Xo = Xe + 2 * QM;
    u16* S  = Xo + 2 * QM;
    u16* D  = S + 2 * QM;
    u16* We = Xe;
    u16* Wo = Xo;
    u16* S2 = S;
    u16* D2 = D;

    k_gencos2<<<2048, 256, 0, stream>>>(Ce, Co);
    k_transpose_split<<<4096, 256, 0, stream>>>(X, Xe, Xo);
    gemm256h<32, 4><<<256, 512, 0, stream>>>(Ce, Co, Xe, Xo, S);
    k_bfly1<<<4096, 256, 0, stream>>>(S, D, We, Wo);
    gemm256h<32, 3><<<256, 512, 0, stream>>>(We, Wo, Ce, Co, S2);
    k_bfly2<<<4096, 256, 0, stream>>>(S2, D2, Y);
}